// Round 2
// baseline (670.085 us; speedup 1.0000x reference)
//
#include <hip/hip_runtime.h>
#include <hip/hip_bf16.h>

// MultiCrossAttention: B=4, T=2048, C=768, H=12, HS=64
// cvt x/mem -> bf16 ; transpose weights -> [N][K] bf16 ;
// GEMM q ; GEMM kv (V written transposed [B,H,64,T]) ; flash attn (no K/V LDS,
// direct L2 fragment reads, barrier-free) ; GEMM out.

#define B_  4
#define T_  2048
#define C_  768
#define H_  12
#define HS_ 64

typedef __attribute__((ext_vector_type(8))) short short8;   // 8 bf16 (4 VGPRs)
typedef __attribute__((ext_vector_type(4))) float f32x4;

__device__ __forceinline__ short f2bf(float f) {
    __hip_bfloat16 h = __float2bfloat16(f);
    return *reinterpret_cast<short*>(&h);
}

// ---------------- prepass kernels ----------------

__global__ void cvt_f32_to_bf16(const float* __restrict__ in, short* __restrict__ out, int n4) {
    int i = blockIdx.x * blockDim.x + threadIdx.x;
    if (i >= n4) return;
    float4 v = reinterpret_cast<const float4*>(in)[i];
    short4 o;
    o.x = f2bf(v.x); o.y = f2bf(v.y); o.z = f2bf(v.z); o.w = f2bf(v.w);
    reinterpret_cast<short4*>(out)[i] = o;
}

// out[n][k] = bf16(in[k][n]); in is [K][N] f32, out is [N][K] bf16
__global__ void wtrans_bf16(const float* __restrict__ in, short* __restrict__ out, int K, int N) {
    int idx = blockIdx.x * blockDim.x + threadIdx.x;
    if (idx >= K * N) return;
    int n = idx / K, k = idx - n * K;
    out[idx] = f2bf(in[(size_t)k * N + n]);
}

// ---------------- GEMM: C[M][N] = A[M][K] @ BT[N][K]^T + bias ----------------
// 128x128 block tile, 4 waves (2x2), each wave 64x64 (4x4 frags of 16x16), BK=64.
// WRITE_VT: cols >= 768 are the V projection -> write transposed to vt[B,H,64,T].

template<int OUT_F32, int WRITE_VT>
__global__ void gemm_bf16_bt(const short* __restrict__ A, const short* __restrict__ BT,
                             const float* __restrict__ bias, void* __restrict__ out,
                             short* __restrict__ vt,
                             int M, int N, int K, int ldo) {
    __shared__ short As[128][72];
    __shared__ short Bs[128][72];
    const int m0 = blockIdx.y * 128;
    const int n0 = blockIdx.x * 128;
    const int t  = threadIdx.x;
    const int wid = t >> 6;
    const int wm = wid >> 1, wn = wid & 1;
    const int lane = t & 63;
    const int lr = lane & 15;
    const int lk = (lane >> 4) * 8;

    f32x4 acc[4][4] = {};

    const int sr = t >> 2;         // 0..63
    const int sc = (t & 3) * 16;   // 0,16,32,48 (shorts)

    for (int k0 = 0; k0 < K; k0 += 64) {
        __syncthreads();
        #pragma unroll
        for (int rr = 0; rr < 128; rr += 64) {
            int r = sr + rr;
            const short* ga = &A [(size_t)(m0 + r) * K + k0 + sc];
            const short* gb = &BT[(size_t)(n0 + r) * K + k0 + sc];
            uint4 a0 = *reinterpret_cast<const uint4*>(ga);
            uint4 a1 = *reinterpret_cast<const uint4*>(ga + 8);
            uint4 b0 = *reinterpret_cast<const uint4*>(gb);
            uint4 b1 = *reinterpret_cast<const uint4*>(gb + 8);
            *reinterpret_cast<uint4*>(&As[r][sc])     = a0;
            *reinterpret_cast<uint4*>(&As[r][sc + 8]) = a1;
            *reinterpret_cast<uint4*>(&Bs[r][sc])     = b0;
            *reinterpret_cast<uint4*>(&Bs[r][sc + 8]) = b1;
        }
        __syncthreads();

        #pragma unroll
        for (int ks = 0; ks < 2; ++ks) {
            const int kk = ks * 32 + lk;
            short8 a[4], b[4];
            #pragma unroll
            for (int m = 0; m < 4; ++m)
                a[m] = *reinterpret_cast<const short8*>(&As[wm*64 + m*16 + lr][kk]);
            #pragma unroll
            for (int n = 0; n < 4; ++n)
                b[n] = *reinterpret_cast<const short8*>(&Bs[wn*64 + n*16 + lr][kk]);
            #pragma unroll
            for (int m = 0; m < 4; ++m)
                #pragma unroll
                for (int n = 0; n < 4; ++n)
                    acc[m][n] = __builtin_amdgcn_mfma_f32_16x16x32_bf16(a[m], b[n], acc[m][n], 0, 0, 0);
        }
    }

    // epilogue: D layout col = lane&15, row = (lane>>4)*4 + j   [m89-verified]
    const int rb = m0 + wm * 64;
    const int cb = n0 + wn * 64;
    const int rj = (lane >> 4) * 4;
    #pragma unroll
    for (int n = 0; n < 4; ++n) {
        const int col = cb + n * 16 + lr;
        const float bv = bias[col];
        #pragma unroll
        for (int m = 0; m < 4; ++m) {
            #pragma unroll
            for (int j = 0; j < 4; ++j) {
                const int row = rb + m * 16 + rj + j;
                const float v = acc[m][n][j] + bv;
                if (WRITE_VT && col >= 768) {
                    const int vd = col - 768;
                    const int hh = vd >> 6, dd = vd & 63;
                    const int bb = row >> 11, tt = row & 2047;
                    vt[(((size_t)bb * H_ + hh) * HS_ + dd) * T_ + tt] = f2bf(v);
                } else if (OUT_F32) {
                    reinterpret_cast<float*>(out)[(size_t)row * ldo + col] = v;
                } else {
                    reinterpret_cast<short*>(out)[(size_t)row * ldo + col] = f2bf(v);
                }
            }
        }
    }
}

// ---------------- flash attention (barrier-free) ----------------
// grid (T/128, H, B), block 256 (4 waves). Wave w owns 32 q-rows.
// K fragments and V^T fragments read directly from global (L2-resident).
// P goes through wave-private XOR-swizzled LDS [32][80].

__device__ __forceinline__ short* plds(short* base, int row, int col) {
    int byte = (row * 80 + col) * 2;
    byte ^= ((row >> 2) & 3) << 4;   // spread b128 reads across bank quads
    return reinterpret_cast<short*>(reinterpret_cast<char*>(base) + byte);
}

__global__ void attn_fwd2(const short* __restrict__ qb, const short* __restrict__ kvb,
                          const short* __restrict__ vtb, short* __restrict__ yb) {
    __shared__ short Pl[4][32 * 80];

    const int b = blockIdx.z, h = blockIdx.y;
    const int q0 = blockIdx.x * 128;
    const int t = threadIdx.x;
    const int w = t >> 6;
    const int lane = t & 63;
    const int lr = lane & 15;
    const int g = lane >> 4;
    short* pb = &Pl[w][0];

    // Q fragments in registers for the whole KV loop: rows m*16+lr, k = ks*32+g*8
    short8 aq[2][2];
    #pragma unroll
    for (int m = 0; m < 2; ++m)
        #pragma unroll
        for (int ks = 0; ks < 2; ++ks)
            aq[m][ks] = *reinterpret_cast<const short8*>(
                &qb[(size_t)(b * T_ + q0 + w * 32 + m * 16 + lr) * C_ + h * HS_ + ks * 32 + g * 8]);

    f32x4 acc[2][4] = {};
    float mrun[2][4], lrun[2][4];
    #pragma unroll
    for (int m = 0; m < 2; ++m)
        #pragma unroll
        for (int j = 0; j < 4; ++j) { mrun[m][j] = -1e30f; lrun[m][j] = 0.f; }

    const short* Kb = kvb + (size_t)b * T_ * (2 * C_) + h * HS_;
    const short* Vb = vtb + (size_t)(b * H_ + h) * HS_ * T_;

    constexpr float cs = 0.18033688f;   // log2(e) / sqrt(64)

    for (int kv0 = 0; kv0 < T_; kv0 += 64) {
        // K fragments direct from global: rows kv0+n*16+lr, k = ks*32+g*8
        short8 bk[4][2];
        #pragma unroll
        for (int n = 0; n < 4; ++n)
            #pragma unroll
            for (int ks = 0; ks < 2; ++ks)
                bk[n][ks] = *reinterpret_cast<const short8*>(
                    &Kb[(size_t)(kv0 + n * 16 + lr) * (2 * C_) + ks * 32 + g * 8]);

        // S = Q K^T (raw, scale folded into exp2 constant)
        f32x4 s[2][4] = {};
        #pragma unroll
        for (int ks = 0; ks < 2; ++ks)
            #pragma unroll
            for (int m = 0; m < 2; ++m)
                #pragma unroll
                for (int n = 0; n < 4; ++n)
                    s[m][n] = __builtin_amdgcn_mfma_f32_16x16x32_bf16(aq[m][ks], bk[n][ks], s[m][n], 0, 0, 0);

        // online softmax; lane holds rows m*16+g*4+j, cols n*16+lr
        #pragma unroll
        for (int m = 0; m < 2; ++m) {
            #pragma unroll
            for (int j = 0; j < 4; ++j) {
                float mx = fmaxf(fmaxf(s[m][0][j], s[m][1][j]), fmaxf(s[m][2][j], s[m][3][j]));
                #pragma unroll
                for (int off = 8; off >= 1; off >>= 1)
                    mx = fmaxf(mx, __shfl_xor(mx, off, 64));
                const float mnew = fmaxf(mrun[m][j], mx);
                const float corr = exp2f((mrun[m][j] - mnew) * cs);
                float psum = 0.f;
                #pragma unroll
                for (int n = 0; n < 4; ++n) {
                    float p = exp2f((s[m][n][j] - mnew) * cs);
                    s[m][n][j] = p;
                    psum += p;
                }
                #pragma unroll
                for (int off = 8; off >= 1; off >>= 1)
                    psum += __shfl_xor(psum, off, 64);
                lrun[m][j] = lrun[m][j] * corr + psum;
                mrun[m][j] = mnew;
                #pragma unroll
                for (int n = 0; n < 4; ++n) acc[m][n][j] *= corr;
            }
        }

        // P -> wave-private LDS (bf16), swizzled
        #pragma unroll
        for (int m = 0; m < 2; ++m)
            #pragma unroll
            for (int n = 0; n < 4; ++n)
                #pragma unroll
                for (int j = 0; j < 4; ++j)
                    *plds(pb, m * 16 + g * 4 + j, n * 16 + lr) = f2bf(s[m][n][j]);

        // Y += P @ V  (V^T fragments direct from global: rows = d, cols = kv)
        #pragma unroll
        for (int ks = 0; ks < 2; ++ks) {
            #pragma unroll
            for (int m = 0; m < 2; ++m) {
                short8 ap = *reinterpret_cast<const short8*>(plds(pb, m * 16 + lr, ks * 32 + g * 8));
                #pragma unroll
                for (int n = 0; n < 4; ++n) {
                    short8 bv = *reinterpret_cast<const short8*>(
                        &Vb[(size_t)(n * 16 + lr) * T_ + kv0 + ks * 32 + g * 8]);
                    acc[m][n] = __builtin_amdgcn_mfma_f32_16x16x32_bf16(ap, bv, acc[m][n], 0, 0, 0);
                }
            }
        }
    }

    // epilogue: y[row][d] = acc / l
    #pragma unroll
    for (int m = 0; m < 2; ++m) {
        #pragma unroll
        for (int j = 0; j < 4; ++j) {
            const float inv = 1.f / lrun[m][j];
            const size_t row = (size_t)(b * T_ + q0 + w * 32 + m * 16 + g * 4 + j);
            #pragma unroll
            for (int n = 0; n < 4; ++n)
                yb[row * C_ + h * HS_ + n * 16 + lr] = f2bf(acc[m][n][j] * inv);
        }
    }
}

// ---------------- launch ----------------

extern "C" void kernel_launch(void* const* d_in, const int* in_sizes, int n_in,
                              void* d_out, int out_size, void* d_ws, size_t ws_size,
                              hipStream_t stream) {
    const float* x      = (const float*)d_in[0];
    const float* memory = (const float*)d_in[1];
    const float* Wq     = (const float*)d_in[2];
    const float* bq     = (const float*)d_in[3];
    const float* Wkv    = (const float*)d_in[4];
    const float* bkv    = (const float*)d_in[5];
    const float* Wproj  = (const float*)d_in[6];
    const float* bproj  = (const float*)d_in[7];

    char* ws = (char*)d_ws;
    size_t off = 0;
    auto alloc = [&](size_t bytes) { char* p = ws + off; off += (bytes + 255) & ~(size_t)255; return p; };
    short* xb   = (short*)alloc((size_t)8192 * 768 * 2);   // x bf16, reused as y after attention
    short* memb = (short*)alloc((size_t)8192 * 768 * 2);
    short* qb   = (short*)alloc((size_t)8192 * 768 * 2);
    short* kvb  = (short*)alloc((size_t)8192 * 1536 * 2);  // K half valid; V half unused
    short* vtb  = (short*)alloc((size_t)B_ * H_ * HS_ * T_ * 2);  // V transposed [B,H,64,T]
    short* WqT  = (short*)alloc((size_t)768 * 768 * 2);
    short* WkvT = (short*)alloc((size_t)1536 * 768 * 2);
    short* WpT  = (short*)alloc((size_t)768 * 768 * 2);

    const int n = 8192 * 768;
    cvt_f32_to_bf16<<<n/4/256, 256, 0, stream>>>(x, xb, n/4);
    cvt_f32_to_bf16<<<n/4/256, 256, 0, stream>>>(memory, memb, n/4);
    wtrans_bf16<<<(768*768  + 255)/256, 256, 0, stream>>>(Wq,    WqT,  768, 768);
    wtrans_bf16<<<(768*1536 + 255)/256, 256, 0, stream>>>(Wkv,   WkvT, 768, 1536);
    wtrans_bf16<<<(768*768  + 255)/256, 256, 0, stream>>>(Wproj, WpT,  768, 768);

    gemm_bf16_bt<0,0><<<dim3( 6, 64), 256, 0, stream>>>(xb,   WqT,  bq,   qb,  nullptr, 8192,  768, 768,  768);
    gemm_bf16_bt<0,1><<<dim3(12, 64), 256, 0, stream>>>(memb, WkvT, bkv,  kvb, vtb,     8192, 1536, 768, 1536);
    attn_fwd2<<<dim3(T_/128, H_, B_), 256, 0, stream>>>(qb, kvb, vtb, xb /* y reuses xb */);
    gemm_bf16_bt<1,0><<<dim3( 6, 64), 256, 0, stream>>>(xb,   WpT,  bproj, d_out, nullptr, 8192, 768, 768, 768);
}

// Round 4
// 494.519 us; speedup vs baseline: 1.3550x; 1.3550x over previous
//
#include <hip/hip_runtime.h>
#include <hip/hip_bf16.h>

// MultiCrossAttention: B=4, T=2048, C=768, H=12, HS=64
// cvt x/mem -> bf16 ; transpose weights -> [N][K] bf16 ;
// GEMM q ; GEMM kv (V written transposed [B,H,64,T]) ;
// flash attn (K + V^T staged in LDS, vectorized, XCD-swizzled grid) ; GEMM out.

#define B_  4
#define T_  2048
#define C_  768
#define H_  12
#define HS_ 64

typedef __attribute__((ext_vector_type(8))) short short8;   // 8 bf16 (4 VGPRs)
typedef __attribute__((ext_vector_type(4))) float f32x4;

__device__ __forceinline__ short f2bf(float f) {
    __hip_bfloat16 h = __float2bfloat16(f);
    return *reinterpret_cast<short*>(&h);
}

// ---------------- prepass kernels ----------------

__global__ void cvt_f32_to_bf16(const float* __restrict__ in, short* __restrict__ out, int n4) {
    int i = blockIdx.x * blockDim.x + threadIdx.x;
    if (i >= n4) return;
    float4 v = reinterpret_cast<const float4*>(in)[i];
    short4 o;
    o.x = f2bf(v.x); o.y = f2bf(v.y); o.z = f2bf(v.z); o.w = f2bf(v.w);
    reinterpret_cast<short4*>(out)[i] = o;
}

// out[n][k] = bf16(in[k][n]); in is [K][N] f32, out is [N][K] bf16
__global__ void wtrans_bf16(const float* __restrict__ in, short* __restrict__ out, int K, int N) {
    int idx = blockIdx.x * blockDim.x + threadIdx.x;
    if (idx >= K * N) return;
    int n = idx / K, k = idx - n * K;
    out[idx] = f2bf(in[(size_t)k * N + n]);
}

// ---------------- GEMM: C[M][N] = A[M][K] @ BT[N][K]^T + bias ----------------

template<int OUT_F32, int WRITE_VT>
__global__ void gemm_bf16_bt(const short* __restrict__ A, const short* __restrict__ BT,
                             const float* __restrict__ bias, void* __restrict__ out,
                             short* __restrict__ vt,
                             int M, int N, int K, int ldo) {
    __shared__ short As[128][72];
    __shared__ short Bs[128][72];
    const int m0 = blockIdx.y * 128;
    const int n0 = blockIdx.x * 128;
    const int t  = threadIdx.x;
    const int wid = t >> 6;
    const int wm = wid >> 1, wn = wid & 1;
    const int lane = t & 63;
    const int lr = lane & 15;
    const int lk = (lane >> 4) * 8;

    f32x4 acc[4][4] = {};

    const int sr = t >> 2;         // 0..63
    const int sc = (t & 3) * 16;   // 0,16,32,48 (shorts)

    for (int k0 = 0; k0 < K; k0 += 64) {
        __syncthreads();
        #pragma unroll
        for (int rr = 0; rr < 128; rr += 64) {
            int r = sr + rr;
            const short* ga = &A [(size_t)(m0 + r) * K + k0 + sc];
            const short* gb = &BT[(size_t)(n0 + r) * K + k0 + sc];
            uint4 a0 = *reinterpret_cast<const uint4*>(ga);
            uint4 a1 = *reinterpret_cast<const uint4*>(ga + 8);
            uint4 b0 = *reinterpret_cast<const uint4*>(gb);
            uint4 b1 = *reinterpret_cast<const uint4*>(gb + 8);
            *reinterpret_cast<uint4*>(&As[r][sc])     = a0;
            *reinterpret_cast<uint4*>(&As[r][sc + 8]) = a1;
            *reinterpret_cast<uint4*>(&Bs[r][sc])     = b0;
            *reinterpret_cast<uint4*>(&Bs[r][sc + 8]) = b1;
        }
        __syncthreads();

        #pragma unroll
        for (int ks = 0; ks < 2; ++ks) {
            const int kk = ks * 32 + lk;
            short8 a[4], b[4];
            #pragma unroll
            for (int m = 0; m < 4; ++m)
                a[m] = *reinterpret_cast<const short8*>(&As[wm*64 + m*16 + lr][kk]);
            #pragma unroll
            for (int n = 0; n < 4; ++n)
                b[n] = *reinterpret_cast<const short8*>(&Bs[wn*64 + n*16 + lr][kk]);
            #pragma unroll
            for (int m = 0; m < 4; ++m)
                #pragma unroll
                for (int n = 0; n < 4; ++n)
                    acc[m][n] = __builtin_amdgcn_mfma_f32_16x16x32_bf16(a[m], b[n], acc[m][n], 0, 0, 0);
        }
    }

    const int rb = m0 + wm * 64;
    const int cb = n0 + wn * 64;
    const int rj = (lane >> 4) * 4;
    #pragma unroll
    for (int n = 0; n < 4; ++n) {
        const int col = cb + n * 16 + lr;
        const float bv = bias[col];
        #pragma unroll
        for (int m = 0; m < 4; ++m) {
            #pragma unroll
            for (int j = 0; j < 4; ++j) {
                const int row = rb + m * 16 + rj + j;
                const float v = acc[m][n][j] + bv;
                if (WRITE_VT && col >= 768) {
                    const int vd = col - 768;
                    const int hh = vd >> 6, dd = vd & 63;
                    const int bb = row >> 11, tt = row & 2047;
                    vt[(((size_t)bb * H_ + hh) * HS_ + dd) * T_ + tt] = f2bf(v);
                } else if (OUT_F32) {
                    reinterpret_cast<float*>(out)[(size_t)row * ldo + col] = v;
                } else {
                    reinterpret_cast<short*>(out)[(size_t)row * ldo + col] = f2bf(v);
                }
            }
        }
    }
}

// ---------------- flash attention ----------------
// 1D grid 768 = 16 qblk x 48 pairs, id = qblk*48 + pair -> all q-blocks of one
// (b,h) share id%8 (same XCD). Block 256 (4 waves), wave owns 32 q-rows.

__device__ __forceinline__ short* plds(short* base, int row, int col) {
    int byte = (row * 80 + col) * 2;
    byte ^= ((row >> 2) & 3) << 4;
    return reinterpret_cast<short*>(reinterpret_cast<char*>(base) + byte);
}

__global__ void attn_fwd3(const short* __restrict__ qb, const short* __restrict__ kvb,
                          const short* __restrict__ vtb, short* __restrict__ yb) {
    __shared__ short Ks[64][72];
    __shared__ short Vt[64][72];
    __shared__ short Pl[4][32 * 80];

    const int id = blockIdx.x;
    const int pair = id % 48;        // b*H + h
    const int b = pair / H_, h = pair % H_;
    const int q0 = (id / 48) * 128;
    const int t = threadIdx.x;
    const int w = t >> 6;
    const int lane = t & 63;
    const int lr = lane & 15;
    const int g = lane >> 4;
    short* pb = &Pl[w][0];

    const int str = t >> 2;          // staging row 0..63 (4 threads/row)
    const int stc = (t & 3) * 16;    // staging col base (shorts); each thread does 2 uint4

    short8 aq[2][2];
    #pragma unroll
    for (int m = 0; m < 2; ++m)
        #pragma unroll
        for (int ks = 0; ks < 2; ++ks)
            aq[m][ks] = *reinterpret_cast<const short8*>(
                &qb[(size_t)(b * T_ + q0 + w * 32 + m * 16 + lr) * C_ + h * HS_ + ks * 32 + g * 8]);

    f32x4 acc[2][4] = {};
    float mrun[2][4], lrun[2][4];
    #pragma unroll
    for (int m = 0; m < 2; ++m)
        #pragma unroll
        for (int j = 0; j < 4; ++j) { mrun[m][j] = -1e30f; lrun[m][j] = 0.f; }

    const short* Kb = kvb + (size_t)b * T_ * (2 * C_) + h * HS_;
    const short* Vb = vtb + (size_t)(b * H_ + h) * HS_ * T_;

    constexpr float cs = 0.18033688f;   // log2(e) / sqrt(64)

    for (int kv0 = 0; kv0 < T_; kv0 += 64) {
        __syncthreads();
        {
            const short* gk = &Kb[(size_t)(kv0 + str) * (2 * C_) + stc];
            const short* gv = &Vb[(size_t)str * T_ + kv0 + stc];
            uint4 k0v = *reinterpret_cast<const uint4*>(gk);
            uint4 k1v = *reinterpret_cast<const uint4*>(gk + 8);
            uint4 v0v = *reinterpret_cast<const uint4*>(gv);
            uint4 v1v = *reinterpret_cast<const uint4*>(gv + 8);
            *reinterpret_cast<uint4*>(&Ks[str][stc])     = k0v;
            *reinterpret_cast<uint4*>(&Ks[str][stc + 8]) = k1v;
            *reinterpret_cast<uint4*>(&Vt[str][stc])     = v0v;
            *reinterpret_cast<uint4*>(&Vt[str][stc + 8]) = v1v;
        }
        __syncthreads();

        f32x4 s[2][4] = {};
        #pragma unroll
        for (int ks = 0; ks < 2; ++ks) {
            #pragma unroll
            for (int n = 0; n < 4; ++n) {
                short8 bk = *reinterpret_cast<const short8*>(&Ks[n * 16 + lr][ks * 32 + g * 8]);
                #pragma unroll
                for (int m = 0; m < 2; ++m)
                    s[m][n] = __builtin_amdgcn_mfma_f32_16x16x32_bf16(aq[m][ks], bk, s[m][n], 0, 0, 0);
            }
        }

        #pragma unroll
        for (int m = 0; m < 2; ++m) {
            #pragma unroll
            for (int j = 0; j < 4; ++j) {
                float mx = fmaxf(fmaxf(s[m][0][j], s[m][1][j]), fmaxf(s[m][2][j], s[m][3][j]));
                #pragma unroll
                for (int off = 8; off >= 1; off >>= 1)
                    mx = fmaxf(mx, __shfl_xor(mx, off, 64));
                const float mnew = fmaxf(mrun[m][j], mx);
                const float corr = exp2f((mrun[m][j] - mnew) * cs);
                float psum = 0.f;
                #pragma unroll
                for (int n = 0; n < 4; ++n) {
                    float p = exp2f((s[m][n][j] - mnew) * cs);
                    s[m][n][j] = p;
                    psum += p;
                }
                #pragma unroll
                for (int off = 8; off >= 1; off >>= 1)
                    psum += __shfl_xor(psum, off, 64);
                lrun[m][j] = lrun[m][j] * corr + psum;
                mrun[m][j] = mnew;
                #pragma unroll
                for (int n = 0; n < 4; ++n) acc[m][n][j] *= corr;
            }
        }

        #pragma unroll
        for (int m = 0; m < 2; ++m)
            #pragma unroll
            for (int n = 0; n < 4; ++n)
                #pragma unroll
                for (int j = 0; j < 4; ++j)
                    *plds(pb, m * 16 + g * 4 + j, n * 16 + lr) = f2bf(s[m][n][j]);

        #pragma unroll
        for (int ks = 0; ks < 2; ++ks) {
            #pragma unroll
            for (int n = 0; n < 4; ++n) {
                short8 bv = *reinterpret_cast<const short8*>(&Vt[n * 16 + lr][ks * 32 + g * 8]);
                #pragma unroll
                for (int m = 0; m < 2; ++m) {
                    short8 ap = *reinterpret_cast<const short8*>(plds(pb, m * 16 + lr, ks * 32 + g * 8));
                    acc[m][n] = __builtin_amdgcn_mfma_f32_16x16x32_bf16(ap, bv, acc[m][n], 0, 0, 0);
                }
            }
        }
    }

    #pragma unroll
    for (int m = 0; m < 2; ++m) {
        #pragma unroll
        for (int j = 0; j < 4; ++j) {
            const float inv = 1.f / lrun[m][j];
            const size_t row = (size_t)(b * T_ + q0 + w * 32 + m * 16 + g * 4 + j);
            #pragma unroll
            for (int n = 0; n < 4; ++n)
                yb[row * C_ + h * HS_ + n * 16 + lr] = f2bf(acc[m][n][j] * inv);
        }
    }
}

// ---------------- launch ----------------

extern "C" void kernel_launch(void* const* d_in, const int* in_sizes, int n_in,
                              void* d_out, int out_size, void* d_ws, size_t ws_size,
                              hipStream_t stream) {
    const float* x      = (const float*)d_in[0];
    const float* memory = (const float*)d_in[1];
    const float* Wq     = (const float*)d_in[2];
    const float* bq     = (const float*)d_in[3];
    const float* Wkv    = (const float*)d_in[4];
    const float* bkv    = (const float*)d_in[5];
    const float* Wproj  = (const float*)d_in[6];
    const float* bproj  = (const float*)d_in[7];

    char* ws = (char*)d_ws;
    size_t off = 0;
    auto alloc = [&](size_t bytes) { char* p = ws + off; off += (bytes + 255) & ~(size_t)255; return p; };
    short* xb   = (short*)alloc((size_t)8192 * 768 * 2);   // x bf16, reused as y after attention
    short* memb = (short*)alloc((size_t)8192 * 768 * 2);
    short* qb   = (short*)alloc((size_t)8192 * 768 * 2);
    short* kvb  = (short*)alloc((size_t)8192 * 1536 * 2);  // K half valid; V half unused
    short* vtb  = (short*)alloc((size_t)B_ * H_ * HS_ * T_ * 2);  // V transposed [B,H,64,T]
    short* WqT  = (short*)alloc((size_t)768 * 768 * 2);
    short* WkvT = (short*)alloc((size_t)1536 * 768 * 2);
    short* WpT  = (short*)alloc((size_t)768 * 768 * 2);

    const int n = 8192 * 768;
    cvt_f32_to_bf16<<<n/4/256, 256, 0, stream>>>(x, xb, n/4);
    cvt_f32_to_bf16<<<n/4/256, 256, 0, stream>>>(memory, memb, n/4);
    wtrans_bf16<<<(768*768  + 255)/256, 256, 0, stream>>>(Wq,    WqT,  768, 768);
    wtrans_bf16<<<(768*1536 + 255)/256, 256, 0, stream>>>(Wkv,   WkvT, 768, 1536);
    wtrans_bf16<<<(768*768  + 255)/256, 256, 0, stream>>>(Wproj, WpT,  768, 768);

    gemm_bf16_bt<0,0><<<dim3( 6, 64), 256, 0, stream>>>(xb,   WqT,  bq,   qb,  nullptr, 8192,  768, 768,  768);
    gemm_bf16_bt<0,1><<<dim3(12, 64), 256, 0, stream>>>(memb, WkvT, bkv,  kvb, vtb,     8192, 1536, 768, 1536);
    attn_fwd3<<<dim3(16 * 48), 256, 0, stream>>>(qb, kvb, vtb, xb /* y reuses xb */);
    gemm_bf16_bt<1,0><<<dim3( 6, 64), 256, 0, stream>>>(xb,   WpT,  bproj, d_out, nullptr, 8192, 768, 768, 768);
}